// Round 1
// baseline (6934.566 us; speedup 1.0000x reference)
//
#include <hip/hip_runtime.h>
#include <math.h>

#define T_STEPS 512
#define BATCH   256
#define DFEAT   128
#define DIN     257
#define DINP    288   // 257 padded to multiple of 32 (zeros)
#define HID     1024
#define G3      3072
#define OUTD    128

typedef __bf16 bf16x8 __attribute__((ext_vector_type(8)));
typedef float  f32x4  __attribute__((ext_vector_type(4)));

__device__ __forceinline__ unsigned short f2bf(float f) {
    unsigned int u = __float_as_uint(f);
    u += 0x7FFF + ((u >> 16) & 1);   // round-to-nearest-even
    return (unsigned short)(u >> 16);
}

// Build xt[t][b][c] (bf16, zero-padded to DINP) from x[b][t][d], mask[b][t][d], ti[b][t]
__global__ void build_xt(const float* __restrict__ x, const float* __restrict__ mask,
                         const float* __restrict__ ti, unsigned short* __restrict__ xt) {
    const int N = T_STEPS * BATCH * DINP;
    for (int idx = blockIdx.x * blockDim.x + threadIdx.x; idx < N;
         idx += gridDim.x * blockDim.x) {
        int c   = idx % DINP;
        int rem = idx / DINP;
        int b   = rem % BATCH;
        int t   = rem / BATCH;
        float v;
        if (c < DFEAT)            v = x[(b * T_STEPS + t) * DFEAT + c];
        else if (c < 2 * DFEAT)   v = mask[(b * T_STEPS + t) * DFEAT + (c - DFEAT)];
        else if (c == 2 * DFEAT)  v = ti[b * T_STEPS + t];
        else                      v = 0.f;
        xt[idx] = f2bf(v);
    }
}

// W_ih [3072][257] fp32 -> [3072][288] bf16 zero-padded
__global__ void conv_wih(const float* __restrict__ w, unsigned short* __restrict__ o) {
    const int N = G3 * DINP;
    for (int idx = blockIdx.x * blockDim.x + threadIdx.x; idx < N;
         idx += gridDim.x * blockDim.x) {
        int c = idx % DINP;
        int g = idx / DINP;
        o[idx] = f2bf(c < DIN ? w[g * DIN + c] : 0.f);
    }
}

// W_hh [3072][1024] fp32 -> bf16
__global__ void conv_whh(const float* __restrict__ w, unsigned short* __restrict__ o) {
    const int N = G3 * HID;
    for (int idx = blockIdx.x * blockDim.x + threadIdx.x; idx < N;
         idx += gridDim.x * blockDim.x) {
        o[idx] = f2bf(w[idx]);
    }
}

// One GRU time step. Grid (64, 4): blockIdx.x = 16-unit tile, blockIdx.y = 64-batch tile.
// 256 threads = 4 waves; wave w handles batch rows [bb, bb+16).
// Per wave: 4 accumulators (r, z, i_n, h_n), each one 16x16 MFMA C tile.
#define LDS_STRIDE 264   // 256 + 8 ushorts pad -> 528B row stride -> 2-way bank alias (free)
__global__ __launch_bounds__(256) void gru_step(
    const unsigned short* __restrict__ xt,   // [T][B][DINP] bf16
    const unsigned short* __restrict__ wih,  // [G3][DINP]  bf16
    const unsigned short* __restrict__ whh,  // [G3][HID]   bf16
    const float* __restrict__ b_ih, const float* __restrict__ b_hh,
    const float* __restrict__ h_rd_f, const unsigned short* __restrict__ h_rd_b,
    float* __restrict__ h_wr_f, unsigned short* __restrict__ h_wr_b,
    int t)
{
    __shared__ unsigned short lds[48 * LDS_STRIDE];   // 48 rows (3 gates x 16 units) x 256 K
    const int tid = threadIdx.x;
    const int l   = tid & 63;
    const int w   = tid >> 6;
    const int u0  = blockIdx.x * 16;
    const int bb  = blockIdx.y * 64 + w * 16;
    const int ln  = l & 15;   // A row / B col / D col
    const int q   = l >> 4;   // quad

    f32x4 accR  = {0.f, 0.f, 0.f, 0.f};
    f32x4 accZ  = {0.f, 0.f, 0.f, 0.f};
    f32x4 accIN = {0.f, 0.f, 0.f, 0.f};
    f32x4 accHN = {0.f, 0.f, 0.f, 0.f};

    // ---------- h-part: K = 1024, staged in K=256 chunks ----------
    for (int k0 = 0; k0 < HID; k0 += 256) {
        __syncthreads();
        #pragma unroll
        for (int i = 0; i < 6; i++) {
            int flat = tid + i * 256;          // 0..1535 = 48 rows x 32 (8-elt groups)
            int row  = flat >> 5;              // 0..47
            int col  = (flat & 31) * 8;        // 0..248
            int g = row >> 4, ur = row & 15;
            const unsigned short* src = whh + (size_t)(g * HID + u0 + ur) * HID + k0 + col;
            *(bf16x8*)(&lds[row * LDS_STRIDE + col]) = *(const bf16x8*)src;
        }
        __syncthreads();
        #pragma unroll
        for (int kk = 0; kk < 256; kk += 32) {
            const unsigned short* ap = h_rd_b + (size_t)(bb + ln) * HID + k0 + kk + q * 8;
            bf16x8 a  = *(const bf16x8*)ap;
            bf16x8 br = *(const bf16x8*)(&lds[(0 * 16 + ln) * LDS_STRIDE + kk + q * 8]);
            bf16x8 bz = *(const bf16x8*)(&lds[(1 * 16 + ln) * LDS_STRIDE + kk + q * 8]);
            bf16x8 bn = *(const bf16x8*)(&lds[(2 * 16 + ln) * LDS_STRIDE + kk + q * 8]);
            accR  = __builtin_amdgcn_mfma_f32_16x16x32_bf16(a, br, accR,  0, 0, 0);
            accZ  = __builtin_amdgcn_mfma_f32_16x16x32_bf16(a, bz, accZ,  0, 0, 0);
            accHN = __builtin_amdgcn_mfma_f32_16x16x32_bf16(a, bn, accHN, 0, 0, 0);
        }
    }

    // ---------- x-part: K = 288 (256 + 32), accumulating i_r, i_z, i_n ----------
    const unsigned short* xrow = xt + (size_t)t * BATCH * DINP;
    {
        // chunk 0: k0 = 0, 256 wide
        __syncthreads();
        #pragma unroll
        for (int i = 0; i < 6; i++) {
            int flat = tid + i * 256;
            int row  = flat >> 5;
            int col  = (flat & 31) * 8;
            int g = row >> 4, ur = row & 15;
            const unsigned short* src = wih + (size_t)(g * HID + u0 + ur) * DINP + col;
            *(bf16x8*)(&lds[row * LDS_STRIDE + col]) = *(const bf16x8*)src;
        }
        __syncthreads();
        #pragma unroll
        for (int kk = 0; kk < 256; kk += 32) {
            const unsigned short* ap = xrow + (size_t)(bb + ln) * DINP + kk + q * 8;
            bf16x8 a  = *(const bf16x8*)ap;
            bf16x8 br = *(const bf16x8*)(&lds[(0 * 16 + ln) * LDS_STRIDE + kk + q * 8]);
            bf16x8 bz = *(const bf16x8*)(&lds[(1 * 16 + ln) * LDS_STRIDE + kk + q * 8]);
            bf16x8 bn = *(const bf16x8*)(&lds[(2 * 16 + ln) * LDS_STRIDE + kk + q * 8]);
            accR  = __builtin_amdgcn_mfma_f32_16x16x32_bf16(a, br, accR,  0, 0, 0);
            accZ  = __builtin_amdgcn_mfma_f32_16x16x32_bf16(a, bz, accZ,  0, 0, 0);
            accIN = __builtin_amdgcn_mfma_f32_16x16x32_bf16(a, bn, accIN, 0, 0, 0);
        }
        // chunk 1: k0 = 256, 32 wide
        __syncthreads();
        for (int i = tid; i < 192; i += 256) {      // 48 rows x 4 groups
            int row = i >> 2;
            int col = (i & 3) * 8;
            int g = row >> 4, ur = row & 15;
            const unsigned short* src = wih + (size_t)(g * HID + u0 + ur) * DINP + 256 + col;
            *(bf16x8*)(&lds[row * LDS_STRIDE + col]) = *(const bf16x8*)src;
        }
        __syncthreads();
        {
            const unsigned short* ap = xrow + (size_t)(bb + ln) * DINP + 256 + q * 8;
            bf16x8 a  = *(const bf16x8*)ap;
            bf16x8 br = *(const bf16x8*)(&lds[(0 * 16 + ln) * LDS_STRIDE + q * 8]);
            bf16x8 bz = *(const bf16x8*)(&lds[(1 * 16 + ln) * LDS_STRIDE + q * 8]);
            bf16x8 bn = *(const bf16x8*)(&lds[(2 * 16 + ln) * LDS_STRIDE + q * 8]);
            accR  = __builtin_amdgcn_mfma_f32_16x16x32_bf16(a, br, accR,  0, 0, 0);
            accZ  = __builtin_amdgcn_mfma_f32_16x16x32_bf16(a, bz, accZ,  0, 0, 0);
            accIN = __builtin_amdgcn_mfma_f32_16x16x32_bf16(a, bn, accIN, 0, 0, 0);
        }
    }

    // ---------- epilogue: gates + state update ----------
    // D layout: col = lane&15 (unit), row = (lane>>4)*4 + reg (batch)
    const int gu  = u0 + ln;
    const float bR  = b_ih[gu]           + b_hh[gu];
    const float bZ  = b_ih[HID + gu]     + b_hh[HID + gu];
    const float bIN = b_ih[2 * HID + gu];
    const float bHN = b_hh[2 * HID + gu];
    #pragma unroll
    for (int r = 0; r < 4; r++) {
        int brow = bb + q * 4 + r;
        float pr = accR[r] + bR;
        float pz = accZ[r] + bZ;
        float rg = 1.f / (1.f + expf(-pr));
        float zg = 1.f / (1.f + expf(-pz));
        float ng = tanhf(accIN[r] + bIN + rg * (accHN[r] + bHN));
        float hold = h_rd_f[(size_t)brow * HID + gu];
        float hnew = (1.f - zg) * ng + zg * hold;
        h_wr_f[(size_t)brow * HID + gu] = hnew;
        h_wr_b[(size_t)brow * HID + gu] = f2bf(hnew);
    }
}

// out[b][o] = h[b] . W_out[o] + b_out[o]
__global__ void out_proj(const float* __restrict__ h, const float* __restrict__ Wout,
                         const float* __restrict__ bout, float* __restrict__ out) {
    int b = blockIdx.x;    // 256
    int o = threadIdx.x;   // 128
    const float* hr = h + (size_t)b * HID;
    const float* wr = Wout + (size_t)o * HID;
    float s0 = 0.f, s1 = 0.f, s2 = 0.f, s3 = 0.f;
    for (int u = 0; u < HID; u += 4) {
        s0 += hr[u + 0] * wr[u + 0];
        s1 += hr[u + 1] * wr[u + 1];
        s2 += hr[u + 2] * wr[u + 2];
        s3 += hr[u + 3] * wr[u + 3];
    }
    out[b * OUTD + o] = (s0 + s1) + (s2 + s3) + bout[o];
}

extern "C" void kernel_launch(void* const* d_in, const int* in_sizes, int n_in,
                              void* d_out, int out_size, void* d_ws, size_t ws_size,
                              hipStream_t stream) {
    const float* x     = (const float*)d_in[0];
    const float* mask  = (const float*)d_in[1];
    const float* ti    = (const float*)d_in[2];
    const float* W_ih  = (const float*)d_in[3];
    const float* W_hh  = (const float*)d_in[4];
    const float* b_ih  = (const float*)d_in[5];
    const float* b_hh  = (const float*)d_in[6];
    const float* W_out = (const float*)d_in[7];
    const float* b_out = (const float*)d_in[8];
    float* out = (float*)d_out;

    char* ws = (char*)d_ws;
    size_t off = 0;
    unsigned short* xt  = (unsigned short*)(ws + off); off += (size_t)T_STEPS * BATCH * DINP * 2;
    unsigned short* wih = (unsigned short*)(ws + off); off += (size_t)G3 * DINP * 2;
    unsigned short* whh = (unsigned short*)(ws + off); off += (size_t)G3 * HID * 2;
    float* hf0          = (float*)(ws + off);          off += (size_t)BATCH * HID * 4;
    float* hf1          = (float*)(ws + off);          off += (size_t)BATCH * HID * 4;
    unsigned short* hb0 = (unsigned short*)(ws + off); off += (size_t)BATCH * HID * 2;
    unsigned short* hb1 = (unsigned short*)(ws + off); off += (size_t)BATCH * HID * 2;

    float* hf[2]          = {hf0, hf1};
    unsigned short* hb[2] = {hb0, hb1};

    // zero h state (f32 master + bf16 shadow, both buffers; contiguous region)
    hipMemsetAsync(hf0, 0, (size_t)BATCH * HID * (4 + 4 + 2 + 2), stream);

    build_xt<<<4096, 256, 0, stream>>>(x, mask, ti, xt);
    conv_wih<<<1024, 256, 0, stream>>>(W_ih, wih);
    conv_whh<<<2048, 256, 0, stream>>>(W_hh, whh);

    for (int t = 0; t < T_STEPS; t++) {
        int rd = t & 1, wr = rd ^ 1;
        gru_step<<<dim3(64, 4), 256, 0, stream>>>(xt, wih, whh, b_ih, b_hh,
                                                  hf[rd], hb[rd], hf[wr], hb[wr], t);
    }
    // after t=511 (rd=1, wr=0) the final h is in buffer 0
    out_proj<<<256, 128, 0, stream>>>(hf[0], W_out, b_out, out);
}